// Round 6
// baseline (465.380 us; speedup 1.0000x reference)
//
#include <hip/hip_runtime.h>
#include <hip/hip_bf16.h>
#include <math.h>

// MixerBlock on MI355X — R6: bf16 MFMA GEMMs, 128x128 tiles, BK=64 K-loop
// (half the barrier drains vs BK=32) + XOR-swizzled LDS layout applied on the
// global-fetch side of global_load_lds (lane l fetches chunk (l&7)^(l>>3) so
// fragment ds_read_b128 hits all 8 bank-groups: R5 showed 7.2M conflict
// cycles from the unswizzled 64B-stride layout). k4 = split-K=4 streamed
// partials + fused reduce.
#define B_   64
#define P_   196
#define PPAD 256      // token-K padded to multiple of 64
#define C_   768
#define TM_  384
#define CM_  3072
#define EPSY 0.1f

typedef unsigned short u16;
typedef __attribute__((ext_vector_type(8))) short bf16x8;
typedef __attribute__((ext_vector_type(4))) float f32x4;

__device__ __forceinline__ float bf2f(u16 v) {
    return __uint_as_float(((unsigned int)v) << 16);
}
__device__ __forceinline__ u16 f2bf(float f) {
    unsigned int u = __float_as_uint(f);
    unsigned int rounding = 0x7FFFu + ((u >> 16) & 1u);
    return (u16)((u + rounding) >> 16);
}

__device__ __forceinline__ void gl_lds16(const u16* g, u16* l) {
    __builtin_amdgcn_global_load_lds(
        (const __attribute__((address_space(1))) unsigned int*)g,
        (__attribute__((address_space(3))) unsigned int*)l,
        16, 0, 0);
}

// ---------------- prep ----------------

// transpose x[b,p,c] f32 -> xT[(b*C+c)][PPAD] bf16 (zero-pad p>=196),
// fused xn1[b*C+c] += sum_p bf16(x)^2 (xn1 pre-zeroed).
__global__ __launch_bounds__(256) void k_prep_xT(const float* __restrict__ x,
                                                 u16* __restrict__ xT,
                                                 float* __restrict__ xn1) {
    __shared__ u16 tile[32][33];
    __shared__ float colsum[32];
    const int b = blockIdx.z, p0 = blockIdx.x * 32, c0 = blockIdx.y * 32;
    const int tx = threadIdx.x & 31, ty = threadIdx.x >> 5;
    if (threadIdx.x < 32) colsum[threadIdx.x] = 0.f;
    const float* xb = x + (size_t)b * P_ * C_;
    float s = 0.f;
    #pragma unroll
    for (int r = 0; r < 4; ++r) {
        int p = p0 + ty + r * 8;
        float v = (p < P_) ? xb[(size_t)p * C_ + c0 + tx] : 0.f;
        u16 h = f2bf(v);
        tile[ty + r * 8][tx] = h;
        float vb = bf2f(h);
        s = fmaf(vb, vb, s);
    }
    __syncthreads();
    u16* dst = xT + ((size_t)b * C_ + c0) * PPAD + p0;
    #pragma unroll
    for (int r = 0; r < 4; ++r) {
        int cl = ty + r * 8;
        dst[(size_t)cl * PPAD + tx] = tile[tx][cl];
    }
    atomicAdd(&colsum[tx], s);
    __syncthreads();
    if (threadIdx.x < 32)
        atomicAdd(&xn1[(size_t)b * C_ + c0 + threadIdx.x], colsum[threadIdx.x]);
}

__device__ __forceinline__ void pad_norm_body(const float* in, u16* outb, float* norm,
                                              int rows, int inlen, int outlen,
                                              int bid, int tid) {
    int wave = (bid * 256 + tid) >> 6;
    int lane = tid & 63;
    if (wave >= rows) return;
    const float* src = in + (size_t)wave * inlen;
    u16* dst = outb + (size_t)wave * outlen;
    float s = 0.f;
    for (int i = lane; i < outlen; i += 64) {
        float v = (i < inlen) ? src[i] : 0.f;
        u16 h = f2bf(v);
        dst[i] = h;
        float vv = bf2f(h);
        s = fmaf(vv, vv, s);
    }
    #pragma unroll
    for (int off = 32; off > 0; off >>= 1) s += __shfl_down(s, off, 64);
    if (lane == 0) norm[wave] = s;
}

// merged weight prep: tw pad+norm | cw pad+norm | w2 pad | w4 bf16
__global__ __launch_bounds__(256) void k_prep_weights(
    const float* __restrict__ tw, u16* __restrict__ twb, float* __restrict__ twn,
    const float* __restrict__ cw, u16* __restrict__ cwb, float* __restrict__ cwn,
    const float* __restrict__ w2, u16* __restrict__ w2b,
    const float* __restrict__ w4, u16* __restrict__ w4b) {
    int bid = blockIdx.x, tid = threadIdx.x;
    if (bid < 96) {
        pad_norm_body(tw, twb, twn, TM_, P_, PPAD, bid, tid);
    } else if (bid < 864) {
        pad_norm_body(cw, cwb, cwn, CM_, C_, C_, bid - 96, tid);
    } else if (bid < 1248) {
        int idx = (bid - 864) * 256 + tid;
        int row = idx / TM_;
        w2b[idx] = (row < P_) ? f2bf(w2[(size_t)row * TM_ + (idx % TM_)]) : (u16)0;
    } else {
        int idx = (bid - 1248) * 256 + tid;
        float4 v = ((const float4*)w4)[idx];
        ushort4 o;
        o.x = f2bf(v.x); o.y = f2bf(v.y); o.z = f2bf(v.z); o.w = f2bf(v.w);
        ((ushort4*)w4b)[idx] = o;
    }
}

// ---------------- MFMA mainloop: 128x128 tile, BK=64, swizzled LDS ----------------
// LDS layout: chunk c (8 u16) of row r stored at slot (c ^ (r&7)) of row r
// (row stride 64 u16 = 128 B). Staging: lane l fetches global chunk
// (l&7)^(l>>3) of row (l>>3) so the forced lane-linear LDS dest realizes it.
__device__ __forceinline__ void mfma_mainloop64(
    const u16* __restrict__ A, const u16* __restrict__ B,
    int lda, int ldb, int kiters,
    f32x4 (&acc)[4][4], u16* As, u16* Bs) {
    const int t = threadIdx.x;
    const int w = t >> 6, l = t & 63;
    const int quad = l >> 4, l15 = l & 15;
    const int srow = w * 32 + (l >> 3);           // + u*8 per sub-iter
    const int scol = ((l & 7) ^ (l >> 3)) * 8;    // swizzled global chunk
    u16* dstA = As + w * 2048 + l * 8;
    u16* dstB = Bs + w * 2048 + l * 8;
    const int arow = (w >> 1) * 64 + l15;         // A fragment rows base
    const int brow = (w & 1) * 64 + l15;
    const int sw = (l15 & 7);                     // read-side swizzle key

    for (int it = 0; it < kiters; ++it) {
        const int k0 = it * 64;
        #pragma unroll
        for (int u = 0; u < 4; ++u) {
            gl_lds16(A + (size_t)(srow + u * 8) * lda + k0 + scol, dstA + u * 512);
            gl_lds16(B + (size_t)(srow + u * 8) * ldb + k0 + scol, dstB + u * 512);
        }
        __syncthreads();
        #pragma unroll
        for (int h = 0; h < 2; ++h) {
            const int kx = ((quad + h * 4) ^ sw) * 8;
            bf16x8 af[4], bfr[4];
            #pragma unroll
            for (int i = 0; i < 4; ++i)
                af[i] = *(const bf16x8*)(As + (arow + i * 16) * 64 + kx);
            #pragma unroll
            for (int j = 0; j < 4; ++j)
                bfr[j] = *(const bf16x8*)(Bs + (brow + j * 16) * 64 + kx);
            #pragma unroll
            for (int i = 0; i < 4; ++i)
                #pragma unroll
                for (int j = 0; j < 4; ++j)
                    acc[i][j] = __builtin_amdgcn_mfma_f32_16x16x32_bf16(af[i], bfr[j], acc[i][j], 0, 0, 0);
        }
        __syncthreads();
    }
}

#define MFMA_PROLOGUE64(AP, BP, LDA, LDB, KITERS)                        \
    __shared__ u16 As[128 * 64];                                         \
    __shared__ u16 Bs[128 * 64];                                         \
    const int t = threadIdx.x;                                           \
    const int wid = t >> 6, lane = t & 63;                               \
    const int quad = lane >> 4, l15 = lane & 15;                         \
    const int m0 = blockIdx.x * 128, n0 = blockIdx.y * 128;              \
    f32x4 acc[4][4];                                                     \
    _Pragma("unroll")                                                    \
    for (int i = 0; i < 4; ++i)                                          \
        _Pragma("unroll")                                                \
        for (int j = 0; j < 4; ++j) acc[i][j] = (f32x4){0.f,0.f,0.f,0.f};\
    mfma_mainloop64(AP, BP, LDA, LDB, KITERS, acc, As, Bs);              \
    const int rbase = m0 + (wid >> 1) * 64;                              \
    const int cbase = n0 + (wid & 1) * 64;

// k1: h1[(b*C+c)][t] = yat(xT, twb); M=49152 N=384 K=256
__global__ __launch_bounds__(256) void k1_token_yat(
    const u16* __restrict__ xT, const u16* __restrict__ twb,
    const float* __restrict__ tb, const float* __restrict__ twn,
    const float* __restrict__ xn1, const float* __restrict__ alpha, float sb,
    u16* __restrict__ h1) {
    MFMA_PROLOGUE64(xT + (size_t)m0 * PPAD, twb + (size_t)n0 * PPAD, PPAD, PPAD, PPAD / 64)
    float scale = powf(sqrtf(sb), alpha[0]);
    #pragma unroll
    for (int i = 0; i < 4; ++i) {
        #pragma unroll
        for (int j = 0; j < 4; ++j) {
            int col = cbase + j * 16 + l15;
            float bn = tb[col], wnn = twn[col];
            #pragma unroll
            for (int reg = 0; reg < 4; ++reg) {
                int row = rbase + i * 16 + quad * 4 + reg;
                float dnb = acc[i][j][reg];
                float dot = dnb + bn;
                float dist = wnn + xn1[row] - 2.f * dnb;
                h1[(size_t)row * TM_ + col] = f2bf(scale * dot * dot / (dist + EPSY));
            }
        }
    }
}

// k3: h3[m][n] = yat(x1b, cwb); M=12544 N=3072 K=768
__global__ __launch_bounds__(256) void k3_chan_yat(
    const u16* __restrict__ x1b, const u16* __restrict__ cwb,
    const float* __restrict__ cb, const float* __restrict__ cwn,
    const float* __restrict__ xn2, const float* __restrict__ alpha, float sb,
    u16* __restrict__ h3) {
    MFMA_PROLOGUE64(x1b + (size_t)m0 * C_, cwb + (size_t)n0 * C_, C_, C_, C_ / 64)
    float scale = powf(sqrtf(sb), alpha[0]);
    #pragma unroll
    for (int i = 0; i < 4; ++i) {
        #pragma unroll
        for (int j = 0; j < 4; ++j) {
            int col = cbase + j * 16 + l15;
            float bn = cb[col], wnn = cwn[col];
            #pragma unroll
            for (int reg = 0; reg < 4; ++reg) {
                int row = rbase + i * 16 + quad * 4 + reg;
                float dnb = acc[i][j][reg];
                float dot = dnb + bn;
                float dist = wnn + xn2[row] - 2.f * dnb;
                h3[(size_t)row * CM_ + col] = f2bf(scale * dot * dot / (dist + EPSY));
            }
        }
    }
}

// k2: x1b[b][p][c] = bf16(x + w2 . h1[b]^T + b2); fused xn2 row-norm atomics.
__global__ __launch_bounds__(256) void k2_token_out(
    const u16* __restrict__ w2b, const u16* __restrict__ h1,
    const float* __restrict__ b2, const float* __restrict__ x,
    float* __restrict__ xn2, u16* __restrict__ x1b) {
    const u16* Bz = h1 + (size_t)blockIdx.z * C_ * TM_;
    MFMA_PROLOGUE64(w2b + (size_t)m0 * TM_, Bz + (size_t)n0 * TM_, TM_, TM_, TM_ / 64)
    const float* rz = x + (size_t)blockIdx.z * P_ * C_;
    u16* oz = x1b + (size_t)blockIdx.z * P_ * C_;
    float* xrow = xn2 + (size_t)blockIdx.z * P_;
    #pragma unroll
    for (int i = 0; i < 4; ++i) {
        #pragma unroll
        for (int reg = 0; reg < 4; ++reg) {
            int row = rbase + i * 16 + quad * 4 + reg;
            if (row < P_) {
                float bm = b2[row];
                float s = 0.f;
                #pragma unroll
                for (int j = 0; j < 4; ++j) {
                    int col = cbase + j * 16 + l15;
                    float v = acc[i][j][reg] + bm + rz[(size_t)row * C_ + col];
                    u16 h = f2bf(v);
                    oz[(size_t)row * C_ + col] = h;
                    float vb = bf2f(h);
                    s = fmaf(vb, vb, s);
                }
                s += __shfl_xor(s, 1, 64);
                s += __shfl_xor(s, 2, 64);
                s += __shfl_xor(s, 4, 64);
                s += __shfl_xor(s, 8, 64);
                if (l15 == 0) atomicAdd(&xrow[row], s);
            }
        }
    }
}

// k4 split-K: partial[z] = h3[:, z*KK:] . w4^T slice; streamed fp32 stores.
__global__ __launch_bounds__(256) void k4_split(
    const u16* __restrict__ h3, const u16* __restrict__ w4b,
    float* __restrict__ outp, float* __restrict__ pbuf, int KK) {
    const int kbase = blockIdx.z * KK;
    MFMA_PROLOGUE64(h3 + (size_t)m0 * CM_ + kbase, w4b + (size_t)n0 * CM_ + kbase,
                    CM_, CM_, KK / 64)
    float* dst = (blockIdx.z == 0) ? outp
               : pbuf + (size_t)(blockIdx.z - 1) * ((size_t)B_ * P_ * C_);
    #pragma unroll
    for (int i = 0; i < 4; ++i) {
        #pragma unroll
        for (int j = 0; j < 4; ++j) {
            int col = cbase + j * 16 + l15;
            #pragma unroll
            for (int reg = 0; reg < 4; ++reg) {
                int row = rbase + i * 16 + quad * 4 + reg;
                dst[(size_t)row * C_ + col] = acc[i][j][reg];
            }
        }
    }
}

// reduce: out = out + sum(pbuf[0..NS-2]) + bf2f(x1b) + b4
template <int NS>
__global__ __launch_bounds__(256) void k4_reduce(
    float* __restrict__ outp, const float* __restrict__ pbuf,
    const u16* __restrict__ x1b, const float* __restrict__ b4) {
    int idx = blockIdx.x * 256 + threadIdx.x;      // < B*P*C/4
    int c = (idx * 4) % C_;
    float4 o = ((const float4*)outp)[idx];
    const size_t stride4 = (size_t)B_ * P_ * C_ / 4;
    #pragma unroll
    for (int s = 0; s < NS - 1; ++s) {
        float4 p = ((const float4*)pbuf)[idx + s * stride4];
        o.x += p.x; o.y += p.y; o.z += p.z; o.w += p.w;
    }
    ushort4 r = ((const ushort4*)x1b)[idx];
    o.x += bf2f(r.x) + b4[c + 0];
    o.y += bf2f(r.y) + b4[c + 1];
    o.z += bf2f(r.z) + b4[c + 2];
    o.w += bf2f(r.w) + b4[c + 3];
    ((float4*)outp)[idx] = o;
}

// fallback k4 (tiny ws): 128x64 tile BK=32 (R3 structure, known-correct)
__device__ __forceinline__ void gl_lds16_fb(const u16* g, u16* l) { gl_lds16(g, l); }
__global__ __launch_bounds__(256) void gemm_k4_fb(
    const u16* __restrict__ A, const u16* __restrict__ Bmat,
    const float* __restrict__ biasN, const u16* __restrict__ resB,
    float* __restrict__ Fout) {
    __shared__ u16 As[128 * 32];
    __shared__ u16 Bs[64 * 32];
    const int t = threadIdx.x;
    const int wid = t >> 6, lane = t & 63;
    const int quad = lane >> 4, l15 = lane & 15;
    const int m0 = blockIdx.x * 128, n0 = blockIdx.y * 64;
    f32x4 acc[4][2];
    #pragma unroll
    for (int i = 0; i < 4; ++i)
        #pragma unroll
        for (int j = 0; j < 2; ++j) acc[i][j] = (f32x4){0.f, 0.f, 0.f, 0.f};
    const u16* Aw = As + (wid >> 1) * (64 * 32);
    const u16* Bw = Bs + (wid & 1) * (32 * 32);
    const int arow = t >> 2, akc = (t & 3) * 8;
    for (int k0 = 0; k0 < CM_; k0 += 32) {
        gl_lds16_fb(A + (size_t)(m0 + arow) * CM_ + k0 + akc,      As + wid * 512);
        gl_lds16_fb(A + (size_t)(m0 + 64 + arow) * CM_ + k0 + akc, As + 2048 + wid * 512);
        gl_lds16_fb(Bmat + (size_t)(n0 + arow) * CM_ + k0 + akc,   Bs + wid * 512);
        __syncthreads();
        bf16x8 af[4], bfr[2];
        #pragma unroll
        for (int i = 0; i < 4; ++i)
            af[i] = *(const bf16x8*)(Aw + ((i * 16 + l15) * 32 + quad * 8));
        #pragma unroll
        for (int j = 0; j < 2; ++j)
            bfr[j] = *(const bf16x8*)(Bw + ((j * 16 + l15) * 32 + quad * 8));
        #pragma unroll
        for (int i = 0; i < 4; ++i)
            #pragma unroll
            for (int j = 0; j < 2; ++j)
                acc[i][j] = __builtin_amdgcn_mfma_f32_16x16x32_bf16(af[i], bfr[j], acc[i][j], 0, 0, 0);
        __syncthreads();
    }
    const int rbase = m0 + (wid >> 1) * 64;
    const int cbase = n0 + (wid & 1) * 32;
    #pragma unroll
    for (int i = 0; i < 4; ++i) {
        #pragma unroll
        for (int j = 0; j < 2; ++j) {
            int col = cbase + j * 16 + l15;
            float bn = biasN[col];
            #pragma unroll
            for (int reg = 0; reg < 4; ++reg) {
                int row = rbase + i * 16 + quad * 4 + reg;
                float v = acc[i][j][reg] + bn + bf2f(resB[(size_t)row * C_ + col]);
                Fout[(size_t)row * C_ + col] = v;
            }
        }
    }
}

extern "C" void kernel_launch(void* const* d_in, const int* in_sizes, int n_in,
                              void* d_out, int out_size, void* d_ws, size_t ws_size,
                              hipStream_t stream) {
    const float* x  = (const float*)d_in[0];
    const float* tw = (const float*)d_in[1];
    const float* tb = (const float*)d_in[2];
    const float* ta = (const float*)d_in[3];
    const float* w2 = (const float*)d_in[4];
    const float* b2 = (const float*)d_in[5];
    const float* cw = (const float*)d_in[6];
    const float* cb = (const float*)d_in[7];
    const float* ca = (const float*)d_in[8];
    const float* w4 = (const float*)d_in[9];
    const float* b4 = (const float*)d_in[10];
    float* out = (float*)d_out;

    // ---- workspace layout (aliased) ----
    char* ws = (char*)d_ws;
    u16* h1 = (u16*)ws;                                    // B*C*TM (37.7 MB)
    u16* xT = (u16*)(ws + 37748736);                       // (B*C) x 256 (25.2 MB)
    u16* h3 = (u16*)ws;                                    // (B*P) x CM (77 MB)
    size_t off = 77070336;
    u16* x1b = (u16*)(ws + off); off += (size_t)B_ * P_ * C_ * 2;
    u16* twb = (u16*)(ws + off); off += (size_t)TM_ * PPAD * 2;
    u16* w2b = (u16*)(ws + off); off += (size_t)256 * TM_ * 2;
    u16* cwb = (u16*)(ws + off); off += (size_t)CM_ * C_ * 2;
    u16* w4b = (u16*)(ws + off); off += (size_t)C_ * CM_ * 2;
    float* xn1 = (float*)(ws + off); off += (size_t)B_ * C_ * 4;
    float* xn2 = (float*)(ws + off); off += (size_t)B_ * P_ * 4;
    float* twn = (float*)(ws + off); off += (size_t)TM_ * 4;
    float* cwn = (float*)(ws + off); off += (size_t)CM_ * 4;
    float* pbuf = (float*)(ws + off);                      // split-K partials
    const size_t psz = (size_t)B_ * P_ * C_ * 4;

    int nsplit = 1;
    if (ws_size >= off + 3 * psz)      nsplit = 4;
    else if (ws_size >= off + psz)     nsplit = 2;

    const float SBT = (float)TM_ / logf((float)TM_ + 1.0f);
    const float SBC = (float)CM_ / logf((float)CM_ + 1.0f);

    // ---- prep ----
    hipMemsetAsync(xn1, 0, (size_t)(B_ * C_ + B_ * P_) * 4, stream);
    k_prep_weights<<<3552, 256, 0, stream>>>(tw, twb, twn, cw, cwb, cwn,
                                             w2, w2b, w4, w4b);
    k_prep_xT<<<dim3(PPAD / 32, C_ / 32, B_), 256, 0, stream>>>(x, xT, xn1);

    // ---- k1: M=49152 N=384 K=256 ----
    k1_token_yat<<<dim3(B_ * C_ / 128, TM_ / 128), 256, 0, stream>>>(
        xT, twb, tb, twn, xn1, ta, SBT, h1);

    // ---- k2: M=256 N=768 K=384, per-batch ----
    k2_token_out<<<dim3(2, C_ / 128, B_), 256, 0, stream>>>(
        w2b, h1, b2, x, xn2, x1b);

    // ---- k3: M=12544 N=3072 K=768 ----
    k3_chan_yat<<<dim3(B_ * P_ / 128, CM_ / 128), 256, 0, stream>>>(
        x1b, cwb, cb, cwn, xn2, ca, SBC, h3);

    // ---- k4: M=12544 N=768 K=3072, split-K streamed ----
    if (nsplit > 1) {
        k4_split<<<dim3(B_ * P_ / 128, C_ / 128, nsplit), 256, 0, stream>>>(
            h3, w4b, out, pbuf, CM_ / nsplit);
        int n4 = B_ * P_ * C_ / 4;
        if (nsplit == 4)
            k4_reduce<4><<<(n4 + 255) / 256, 256, 0, stream>>>(out, pbuf, x1b, b4);
        else
            k4_reduce<2><<<(n4 + 255) / 256, 256, 0, stream>>>(out, pbuf, x1b, b4);
    } else {
        gemm_k4_fb<<<dim3(B_ * P_ / 128, C_ / 64), 256, 0, stream>>>(
            h3, w4b, b4, x1b, out);
    }
}

// Round 7
// 421.806 us; speedup vs baseline: 1.1033x; 1.1033x over previous
//
#include <hip/hip_runtime.h>
#include <hip/hip_bf16.h>
#include <math.h>

// MixerBlock on MI355X — R7: R5 mainloop (BK=32, unswizzled LDS — R6 proved the
// 7.2M "conflicts" were the free 2-way kind and the XOR swizzle cost more VALU
// than it saved) + XCD-locality tile swizzle (m-tiles striped mod 8 across
// XCDs so each XCD's A-stripe ~2.5MB lives in its 4MB L2; R5 k3 FETCH was
// 206MB vs 24MB ideal) + bf16 split-K partials for k4 (halves partial traffic;
// absmax slack 0.031 vs 0.109 covers the extra rounding).
#define B_   64
#define P_   196
#define PPAD 224
#define C_   768
#define TM_  384
#define CM_  3072
#define EPSY 0.1f

typedef unsigned short u16;
typedef __attribute__((ext_vector_type(8))) short bf16x8;
typedef __attribute__((ext_vector_type(4))) float f32x4;

__device__ __forceinline__ float bf2f(u16 v) {
    return __uint_as_float(((unsigned int)v) << 16);
}
__device__ __forceinline__ u16 f2bf(float f) {
    unsigned int u = __float_as_uint(f);
    unsigned int rounding = 0x7FFFu + ((u >> 16) & 1u);
    return (u16)((u + rounding) >> 16);
}

__device__ __forceinline__ void gl_lds16(const u16* g, u16* l) {
    __builtin_amdgcn_global_load_lds(
        (const __attribute__((address_space(1))) unsigned int*)g,
        (__attribute__((address_space(3))) unsigned int*)l,
        16, 0, 0);
}

// ---------------- prep ----------------

__global__ __launch_bounds__(256) void k_prep_xT(const float* __restrict__ x,
                                                 u16* __restrict__ xT,
                                                 float* __restrict__ xn1) {
    __shared__ u16 tile[32][33];
    __shared__ float colsum[32];
    const int b = blockIdx.z, p0 = blockIdx.x * 32, c0 = blockIdx.y * 32;
    const int tx = threadIdx.x & 31, ty = threadIdx.x >> 5;
    if (threadIdx.x < 32) colsum[threadIdx.x] = 0.f;
    const float* xb = x + (size_t)b * P_ * C_;
    float s = 0.f;
    #pragma unroll
    for (int r = 0; r < 4; ++r) {
        int p = p0 + ty + r * 8;
        float v = (p < P_) ? xb[(size_t)p * C_ + c0 + tx] : 0.f;
        u16 h = f2bf(v);
        tile[ty + r * 8][tx] = h;
        float vb = bf2f(h);
        s = fmaf(vb, vb, s);
    }
    __syncthreads();
    u16* dst = xT + ((size_t)b * C_ + c0) * PPAD + p0;
    #pragma unroll
    for (int r = 0; r < 4; ++r) {
        int cl = ty + r * 8;
        dst[(size_t)cl * PPAD + tx] = tile[tx][cl];
    }
    atomicAdd(&colsum[tx], s);
    __syncthreads();
    if (threadIdx.x < 32)
        atomicAdd(&xn1[(size_t)b * C_ + c0 + threadIdx.x], colsum[threadIdx.x]);
}

__device__ __forceinline__ void pad_norm_body(const float* in, u16* outb, float* norm,
                                              int rows, int inlen, int outlen,
                                              int bid, int tid) {
    int wave = (bid * 256 + tid) >> 6;
    int lane = tid & 63;
    if (wave >= rows) return;
    const float* src = in + (size_t)wave * inlen;
    u16* dst = outb + (size_t)wave * outlen;
    float s = 0.f;
    for (int i = lane; i < outlen; i += 64) {
        float v = (i < inlen) ? src[i] : 0.f;
        u16 h = f2bf(v);
        dst[i] = h;
        float vv = bf2f(h);
        s = fmaf(vv, vv, s);
    }
    #pragma unroll
    for (int off = 32; off > 0; off >>= 1) s += __shfl_down(s, off, 64);
    if (lane == 0) norm[wave] = s;
}

__global__ __launch_bounds__(256) void k_prep_weights(
    const float* __restrict__ tw, u16* __restrict__ twb, float* __restrict__ twn,
    const float* __restrict__ cw, u16* __restrict__ cwb, float* __restrict__ cwn,
    const float* __restrict__ w2, u16* __restrict__ w2b,
    const float* __restrict__ w4, u16* __restrict__ w4b) {
    int bid = blockIdx.x, tid = threadIdx.x;
    if (bid < 96) {
        pad_norm_body(tw, twb, twn, TM_, P_, PPAD, bid, tid);
    } else if (bid < 864) {
        pad_norm_body(cw, cwb, cwn, CM_, C_, C_, bid - 96, tid);
    } else if (bid < 1248) {
        int idx = (bid - 864) * 256 + tid;
        int row = idx / TM_;
        w2b[idx] = (row < P_) ? f2bf(w2[(size_t)row * TM_ + (idx % TM_)]) : (u16)0;
    } else {
        int idx = (bid - 1248) * 256 + tid;
        float4 v = ((const float4*)w4)[idx];
        ushort4 o;
        o.x = f2bf(v.x); o.y = f2bf(v.y); o.z = f2bf(v.z); o.w = f2bf(v.w);
        ((ushort4*)w4b)[idx] = o;
    }
}

// ---------------- R5 MFMA mainloop: 128x128 tile, BK=32 ----------------
__device__ __forceinline__ void mfma_mainloop(
    const u16* __restrict__ A, const u16* __restrict__ B,
    int lda, int ldb, int kiters,
    f32x4 (&acc)[4][4], u16* As, u16* Bs) {
    const int t = threadIdx.x;
    const int w = t >> 6, l = t & 63;
    const int quad = l >> 4, l15 = l & 15;
    const u16* Aw = As + (w >> 1) * (64 * 32);
    const u16* Bw = Bs + (w & 1) * (64 * 32);
    const int row0 = t >> 2, kc = (t & 3) * 8;
    const int row1 = 64 + row0;

    for (int it = 0; it < kiters; ++it) {
        int k0 = it * 32;
        gl_lds16(A + (size_t)row0 * lda + k0 + kc, As + w * 512);
        gl_lds16(A + (size_t)row1 * lda + k0 + kc, As + 2048 + w * 512);
        gl_lds16(B + (size_t)row0 * ldb + k0 + kc, Bs + w * 512);
        gl_lds16(B + (size_t)row1 * ldb + k0 + kc, Bs + 2048 + w * 512);
        __syncthreads();
        bf16x8 af[4], bfr[4];
        #pragma unroll
        for (int i = 0; i < 4; ++i)
            af[i] = *(const bf16x8*)(Aw + ((i * 16 + l15) * 32 + quad * 8));
        #pragma unroll
        for (int j = 0; j < 4; ++j)
            bfr[j] = *(const bf16x8*)(Bw + ((j * 16 + l15) * 32 + quad * 8));
        #pragma unroll
        for (int i = 0; i < 4; ++i)
            #pragma unroll
            for (int j = 0; j < 4; ++j)
                acc[i][j] = __builtin_amdgcn_mfma_f32_16x16x32_bf16(af[i], bfr[j], acc[i][j], 0, 0, 0);
        __syncthreads();
    }
}

// prologue with explicit tile coords (for XCD swizzle)
#define MFMA_CORE(AP, BP, LDA, LDB, KITERS)                              \
    __shared__ u16 As[128 * 32];                                         \
    __shared__ u16 Bs[128 * 32];                                         \
    const int t = threadIdx.x;                                           \
    const int wid = t >> 6, lane = t & 63;                               \
    const int quad = lane >> 4, l15 = lane & 15;                         \
    f32x4 acc[4][4];                                                     \
    _Pragma("unroll")                                                    \
    for (int i = 0; i < 4; ++i)                                          \
        _Pragma("unroll")                                                \
        for (int j = 0; j < 4; ++j) acc[i][j] = (f32x4){0.f,0.f,0.f,0.f};\
    mfma_mainloop(AP, BP, LDA, LDB, KITERS, acc, As, Bs);                \
    const int rbase = m0 + (wid >> 1) * 64;                              \
    const int cbase = n0 + (wid & 1) * 64;

// k1: h1[(b*C+c)][t] = yat(xT, twb); M=49152 N=384 K=224. grid (8,48,3):
// m-tile = x + y*8 (XCD stripe), n-tile = z.
__global__ __launch_bounds__(256) void k1_token_yat(
    const u16* __restrict__ xT, const u16* __restrict__ twb,
    const float* __restrict__ tb, const float* __restrict__ twn,
    const float* __restrict__ xn1, const float* __restrict__ alpha, float sb,
    u16* __restrict__ h1) {
    const int m0 = (blockIdx.x + blockIdx.y * 8) * 128;
    const int n0 = blockIdx.z * 128;
    MFMA_CORE(xT + (size_t)m0 * PPAD, twb + (size_t)n0 * PPAD, PPAD, PPAD, PPAD / 32)
    float scale = powf(sqrtf(sb), alpha[0]);
    #pragma unroll
    for (int i = 0; i < 4; ++i) {
        #pragma unroll
        for (int j = 0; j < 4; ++j) {
            int col = cbase + j * 16 + l15;
            float bn = tb[col], wnn = twn[col];
            #pragma unroll
            for (int reg = 0; reg < 4; ++reg) {
                int row = rbase + i * 16 + quad * 4 + reg;
                float dnb = acc[i][j][reg];
                float dot = dnb + bn;
                float dist = wnn + xn1[row] - 2.f * dnb;
                h1[(size_t)row * TM_ + col] = f2bf(scale * dot * dot / (dist + EPSY));
            }
        }
    }
}

// k3: h3[m][n] = yat(x1b, cwb); M=12544 N=3072 K=768. grid (8,13,24):
// m-tile = x + y*8 (guard < 98), n-tile = z. Per-XCD A-stripe 2.5MB -> L2.
__global__ __launch_bounds__(256) void k3_chan_yat(
    const u16* __restrict__ x1b, const u16* __restrict__ cwb,
    const float* __restrict__ cb, const float* __restrict__ cwn,
    const float* __restrict__ xn2, const float* __restrict__ alpha, float sb,
    u16* __restrict__ h3) {
    const int mt = blockIdx.x + blockIdx.y * 8;
    if (mt >= B_ * P_ / 128) return;
    const int m0 = mt * 128;
    const int n0 = blockIdx.z * 128;
    MFMA_CORE(x1b + (size_t)m0 * C_, cwb + (size_t)n0 * C_, C_, C_, C_ / 32)
    float scale = powf(sqrtf(sb), alpha[0]);
    #pragma unroll
    for (int i = 0; i < 4; ++i) {
        #pragma unroll
        for (int j = 0; j < 4; ++j) {
            int col = cbase + j * 16 + l15;
            float bn = cb[col], wnn = cwn[col];
            #pragma unroll
            for (int reg = 0; reg < 4; ++reg) {
                int row = rbase + i * 16 + quad * 4 + reg;
                float dnb = acc[i][j][reg];
                float dot = dnb + bn;
                float dist = wnn + xn2[row] - 2.f * dnb;
                h3[(size_t)row * CM_ + col] = f2bf(scale * dot * dot / (dist + EPSY));
            }
        }
    }
}

// k2: x1b[b][p][c] = bf16(x + w2 . h1[b]^T + b2); fused xn2 row-norm atomics.
__global__ __launch_bounds__(256) void k2_token_out(
    const u16* __restrict__ w2b, const u16* __restrict__ h1,
    const float* __restrict__ b2, const float* __restrict__ x,
    float* __restrict__ xn2, u16* __restrict__ x1b) {
    const int m0 = blockIdx.x * 128, n0 = blockIdx.y * 128;
    const u16* Bz = h1 + (size_t)blockIdx.z * C_ * TM_;
    MFMA_CORE(w2b + (size_t)m0 * TM_, Bz + (size_t)n0 * TM_, TM_, TM_, TM_ / 32)
    const float* rz = x + (size_t)blockIdx.z * P_ * C_;
    u16* oz = x1b + (size_t)blockIdx.z * P_ * C_;
    float* xrow = xn2 + (size_t)blockIdx.z * P_;
    #pragma unroll
    for (int i = 0; i < 4; ++i) {
        #pragma unroll
        for (int reg = 0; reg < 4; ++reg) {
            int row = rbase + i * 16 + quad * 4 + reg;
            if (row < P_) {
                float bm = b2[row];
                float s = 0.f;
                #pragma unroll
                for (int j = 0; j < 4; ++j) {
                    int col = cbase + j * 16 + l15;
                    float v = acc[i][j][reg] + bm + rz[(size_t)row * C_ + col];
                    u16 h = f2bf(v);
                    oz[(size_t)row * C_ + col] = h;
                    float vb = bf2f(h);
                    s = fmaf(vb, vb, s);
                }
                s += __shfl_xor(s, 1, 64);
                s += __shfl_xor(s, 2, 64);
                s += __shfl_xor(s, 4, 64);
                s += __shfl_xor(s, 8, 64);
                if (l15 == 0) atomicAdd(&xrow[row], s);
            }
        }
    }
}

// k4 split-K: bf16 partials -> pbuf[ks]. grid (8,13,6*nsplit):
// m-tile = x + y*8 (guard), z -> n = z%6, ks = z/6.
__global__ __launch_bounds__(256) void k4_split(
    const u16* __restrict__ h3, const u16* __restrict__ w4b,
    u16* __restrict__ pbuf, int KK) {
    const int mt = blockIdx.x + blockIdx.y * 8;
    if (mt >= B_ * P_ / 128) return;
    const int m0 = mt * 128;
    const int nz = blockIdx.z;
    const int n0 = (nz % (C_ / 128)) * 128;
    const int ks = nz / (C_ / 128);
    const int kbase = ks * KK;
    MFMA_CORE(h3 + (size_t)m0 * CM_ + kbase, w4b + (size_t)n0 * CM_ + kbase,
              CM_, CM_, KK / 32)
    u16* dst = pbuf + (size_t)ks * ((size_t)B_ * P_ * C_);
    #pragma unroll
    for (int i = 0; i < 4; ++i) {
        #pragma unroll
        for (int j = 0; j < 4; ++j) {
            int col = cbase + j * 16 + l15;
            #pragma unroll
            for (int reg = 0; reg < 4; ++reg) {
                int row = rbase + i * 16 + quad * 4 + reg;
                dst[(size_t)row * C_ + col] = f2bf(acc[i][j][reg]);
            }
        }
    }
}

// reduce: out = sum(bf16 pbuf[0..NS-1]) + bf2f(x1b) + b4
template <int NS>
__global__ __launch_bounds__(256) void k4_reduce(
    float* __restrict__ outp, const u16* __restrict__ pbuf,
    const u16* __restrict__ x1b, const float* __restrict__ b4) {
    int idx = blockIdx.x * 256 + threadIdx.x;      // < B*P*C/4
    int c = (idx * 4) % C_;
    ushort4 r = ((const ushort4*)x1b)[idx];
    float4 o;
    o.x = bf2f(r.x) + b4[c + 0];
    o.y = bf2f(r.y) + b4[c + 1];
    o.z = bf2f(r.z) + b4[c + 2];
    o.w = bf2f(r.w) + b4[c + 3];
    const size_t stride4 = (size_t)B_ * P_ * C_ / 4;
    #pragma unroll
    for (int s = 0; s < NS; ++s) {
        ushort4 p = ((const ushort4*)pbuf)[idx + s * stride4];
        o.x += bf2f(p.x); o.y += bf2f(p.y); o.z += bf2f(p.z); o.w += bf2f(p.w);
    }
    ((float4*)outp)[idx] = o;
}

// fallback k4 (tiny ws): 128x64 tile BK=32
__global__ __launch_bounds__(256) void gemm_k4_fb(
    const u16* __restrict__ A, const u16* __restrict__ Bmat,
    const float* __restrict__ biasN, const u16* __restrict__ resB,
    float* __restrict__ Fout) {
    __shared__ u16 As[128 * 32];
    __shared__ u16 Bs[64 * 32];
    const int t = threadIdx.x;
    const int wid = t >> 6, lane = t & 63;
    const int quad = lane >> 4, l15 = lane & 15;
    const int m0 = blockIdx.x * 128, n0 = blockIdx.y * 64;
    f32x4 acc[4][2];
    #pragma unroll
    for (int i = 0; i < 4; ++i)
        #pragma unroll
        for (int j = 0; j < 2; ++j) acc[i][j] = (f32x4){0.f, 0.f, 0.f, 0.f};
    const u16* Aw = As + (wid >> 1) * (64 * 32);
    const u16* Bw = Bs + (wid & 1) * (32 * 32);
    const int arow = t >> 2, akc = (t & 3) * 8;
    for (int k0 = 0; k0 < CM_; k0 += 32) {
        gl_lds16(A + (size_t)(m0 + arow) * CM_ + k0 + akc,      As + wid * 512);
        gl_lds16(A + (size_t)(m0 + 64 + arow) * CM_ + k0 + akc, As + 2048 + wid * 512);
        gl_lds16(Bmat + (size_t)(n0 + arow) * CM_ + k0 + akc,   Bs + wid * 512);
        __syncthreads();
        bf16x8 af[4], bfr[2];
        #pragma unroll
        for (int i = 0; i < 4; ++i)
            af[i] = *(const bf16x8*)(Aw + ((i * 16 + l15) * 32 + quad * 8));
        #pragma unroll
        for (int j = 0; j < 2; ++j)
            bfr[j] = *(const bf16x8*)(Bw + ((j * 16 + l15) * 32 + quad * 8));
        #pragma unroll
        for (int i = 0; i < 4; ++i)
            #pragma unroll
            for (int j = 0; j < 2; ++j)
                acc[i][j] = __builtin_amdgcn_mfma_f32_16x16x32_bf16(af[i], bfr[j], acc[i][j], 0, 0, 0);
        __syncthreads();
    }
    const int rbase = m0 + (wid >> 1) * 64;
    const int cbase = n0 + (wid & 1) * 32;
    #pragma unroll
    for (int i = 0; i < 4; ++i) {
        #pragma unroll
        for (int j = 0; j < 2; ++j) {
            int col = cbase + j * 16 + l15;
            float bn = biasN[col];
            #pragma unroll
            for (int reg = 0; reg < 4; ++reg) {
                int row = rbase + i * 16 + quad * 4 + reg;
                float v = acc[i][j][reg] + bn + bf2f(resB[(size_t)row * C_ + col]);
                Fout[(size_t)row * C_ + col] = v;
            }
        }
    }
}

extern "C" void kernel_launch(void* const* d_in, const int* in_sizes, int n_in,
                              void* d_out, int out_size, void* d_ws, size_t ws_size,
                              hipStream_t stream) {
    const float* x  = (const float*)d_in[0];
    const float* tw = (const float*)d_in[1];
    const float* tb = (const float*)d_in[2];
    const float* ta = (const float*)d_in[3];
    const float* w2 = (const float*)d_in[4];
    const float* b2 = (const float*)d_in[5];
    const float* cw = (const float*)d_in[6];
    const float* cb = (const float*)d_in[7];
    const float* ca = (const float*)d_in[8];
    const float* w4 = (const float*)d_in[9];
    const float* b4 = (const float*)d_in[10];
    float* out = (float*)d_out;

    // ---- workspace layout (aliased) ----
    char* ws = (char*)d_ws;
    u16* h1 = (u16*)ws;                                    // B*C*TM (37.7 MB)
    u16* xT = (u16*)(ws + 37748736);                       // (B*C) x 224 (22 MB)
    u16* h3 = (u16*)ws;                                    // (B*P) x CM (77 MB)
    size_t off = 77070336;
    u16* x1b = (u16*)(ws + off); off += (size_t)B_ * P_ * C_ * 2;
    u16* twb = (u16*)(ws + off); off += (size_t)TM_ * PPAD * 2;
    u16* w2b = (u16*)(ws + off); off += (size_t)256 * TM_ * 2;
    u16* cwb = (u16*)(ws + off); off += (size_t)CM_ * C_ * 2;
    u16* w4b = (u16*)(ws + off); off += (size_t)C_ * CM_ * 2;
    float* xn1 = (float*)(ws + off); off += (size_t)B_ * C_ * 4;
    float* xn2 = (float*)(ws + off); off += (size_t)B_ * P_ * 4;
    float* twn = (float*)(ws + off); off += (size_t)TM_ * 4;
    float* cwn = (float*)(ws + off); off += (size_t)CM_ * 4;
    u16* pbuf = (u16*)(ws + off);                          // bf16 split-K partials
    const size_t psz = (size_t)B_ * P_ * C_ * 2;           // 19,267,584 per buffer

    int nsplit = 1;
    if (ws_size >= off + 4 * psz)      nsplit = 4;
    else if (ws_size >= off + 2 * psz) nsplit = 2;

    const float SBT = (float)TM_ / logf((float)TM_ + 1.0f);
    const float SBC = (float)CM_ / logf((float)CM_ + 1.0f);

    // ---- prep ----
    hipMemsetAsync(xn1, 0, (size_t)(B_ * C_ + B_ * P_) * 4, stream);
    k_prep_weights<<<3552, 256, 0, stream>>>(tw, twb, twn, cw, cwb, cwn,
                                             w2, w2b, w4, w4b);
    k_prep_xT<<<dim3(PPAD / 32, C_ / 32, B_), 256, 0, stream>>>(x, xT, xn1);

    // ---- k1: M=49152 N=384 K=224 ; XCD-swizzled grid (8,48,3) ----
    k1_token_yat<<<dim3(8, 48, 3), 256, 0, stream>>>(
        xT, twb, tb, twn, xn1, ta, SBT, h1);

    // ---- k2: M=256 N=768 K=384, per-batch ----
    k2_token_out<<<dim3(2, C_ / 128, B_), 256, 0, stream>>>(
        w2b, h1, b2, x, xn2, x1b);

    // ---- k3: M=12544 N=3072 K=768 ; XCD-swizzled grid (8,13,24) ----
    k3_chan_yat<<<dim3(8, 13, 24), 256, 0, stream>>>(
        x1b, cwb, cb, cwn, xn2, ca, SBC, h3);

    // ---- k4: M=12544 N=768 K=3072, split-K bf16 partials ----
    if (nsplit > 1) {
        k4_split<<<dim3(8, 13, (C_ / 128) * nsplit), 256, 0, stream>>>(
            h3, w4b, pbuf, CM_ / nsplit);
        int n4 = B_ * P_ * C_ / 4;
        if (nsplit == 4)
            k4_reduce<4><<<(n4 + 255) / 256, 256, 0, stream>>>(out, pbuf, x1b, b4);
        else
            k4_reduce<2><<<(n4 + 255) / 256, 256, 0, stream>>>(out, pbuf, x1b, b4);
    } else {
        gemm_k4_fb<<<dim3(B_ * P_ / 128, C_ / 64), 256, 0, stream>>>(
            h3, w4b, b4, x1b, out);
    }
}